// Round 7
// baseline (202.244 us; speedup 1.0000x reference)
//
#include <hip/hip_runtime.h>

#define DD 500   // hidden width
#define BB 64    // batch
#define TT 2048  // timesteps (only last matters)
#define KP 128   // pitch/velocity feature width
#define VCHUNKS 32
#define VPSTRIDE 512

// ---------------------------------------------------------------------------
// K0: embed (last timestep only) -> addT[500][64]
// 125 blocks: 4 o-rows x 64 b each, via swizzled-LDS transpose of P/V slices
// ---------------------------------------------------------------------------
__global__ __launch_bounds__(256) void k_embed(
    const float* __restrict__ pitches, const float* __restrict__ velocities,
    const float* __restrict__ durations, const float* __restrict__ steps,
    const float* __restrict__ Wp, const float* __restrict__ bp,
    const float* __restrict__ Wv, const float* __restrict__ bv,
    const float* __restrict__ Wd, const float* __restrict__ bd,
    const float* __restrict__ Wst, const float* __restrict__ bs,
    float* __restrict__ addT)
{
    const int tid = threadIdx.x;
    const int bid = blockIdx.x;

    __shared__ float lds[KP * BB];  // 32 KB; [k][b] at lds[k*64 + ((b+k)&63)]
    const int b = tid & 63;
    const int o = __builtin_amdgcn_readfirstlane(bid * 4 + (tid >> 6));
    const float* __restrict__ wp = Wp + o * KP;
    const float* __restrict__ wv = Wv + o * KP;

    float a0 = 0.f, a1 = 0.f, a2 = 0.f, a3 = 0.f;

    const float4* Psrc = (const float4*)(pitches + (size_t)(TT - 1) * BB * KP);
    const float4* Vsrc = (const float4*)(velocities + (size_t)(TT - 1) * BB * KP);

    // pass 1: pitches
    for (int j = tid; j < BB * KP / 4; j += 256) {
        float4 p = Psrc[j];
        int pb = j >> 5;          // batch row (32 float4 per 128-wide row)
        int k0 = (j & 31) * 4;
        lds[(k0 + 0) * BB + ((pb + k0 + 0) & 63)] = p.x;
        lds[(k0 + 1) * BB + ((pb + k0 + 1) & 63)] = p.y;
        lds[(k0 + 2) * BB + ((pb + k0 + 2) & 63)] = p.z;
        lds[(k0 + 3) * BB + ((pb + k0 + 3) & 63)] = p.w;
    }
    __syncthreads();
    for (int k = 0; k < KP; k += 4) {
        a0 += lds[(k + 0) * BB + ((b + k + 0) & 63)] * wp[k + 0];
        a1 += lds[(k + 1) * BB + ((b + k + 1) & 63)] * wp[k + 1];
        a2 += lds[(k + 2) * BB + ((b + k + 2) & 63)] * wp[k + 2];
        a3 += lds[(k + 3) * BB + ((b + k + 3) & 63)] * wp[k + 3];
    }
    __syncthreads();

    // pass 2: velocities
    for (int j = tid; j < BB * KP / 4; j += 256) {
        float4 p = Vsrc[j];
        int pb = j >> 5;
        int k0 = (j & 31) * 4;
        lds[(k0 + 0) * BB + ((pb + k0 + 0) & 63)] = p.x;
        lds[(k0 + 1) * BB + ((pb + k0 + 1) & 63)] = p.y;
        lds[(k0 + 2) * BB + ((pb + k0 + 2) & 63)] = p.z;
        lds[(k0 + 3) * BB + ((pb + k0 + 3) & 63)] = p.w;
    }
    __syncthreads();
    for (int k = 0; k < KP; k += 4) {
        a0 += lds[(k + 0) * BB + ((b + k + 0) & 63)] * wv[k + 0];
        a1 += lds[(k + 1) * BB + ((b + k + 1) & 63)] * wv[k + 1];
        a2 += lds[(k + 2) * BB + ((b + k + 2) & 63)] * wv[k + 2];
        a3 += lds[(k + 3) * BB + ((b + k + 3) & 63)] * wv[k + 3];
    }

    const float dur = durations[(size_t)(TT - 1) * BB + b];
    const float st  = steps[(size_t)(TT - 1) * BB + b];
    addT[o * BB + b] = bp[o] + bv[o] + bd[o] + bs[o]
                     + dur * Wd[o] + st * Wst[o]
                     + (a0 + a1) + (a2 + a3);
}

// ---------------------------------------------------------------------------
// K1: blocks 0..499 dense rows of W1 (4 waves k-split + LDS reduce);
//     blocks 500..531 vpart chunks (vpart[oc][k] = sum_{o in chunk} W3[o]*Wi[o][k]);
//     block 500 tid 0 zero-inits the dense-2 finalize counter (stream order
//     makes it visible to K2 — no reliance on poisoned ws, no extra dispatch).
// ---------------------------------------------------------------------------
__global__ __launch_bounds__(256) void k_dense1(
    const float* __restrict__ Ain, const float* __restrict__ W,
    const float* __restrict__ bias, float* __restrict__ Aout,
    const float* __restrict__ Wi, const float* __restrict__ W3,
    float* __restrict__ vpart, int* __restrict__ counter)
{
    const int tid = threadIdx.x;
    const int bid = blockIdx.x;

    if (bid >= DD) {
        if (bid == DD && tid == 0) *counter = 0;
        // ---- v-chunk: 16 o-rows, 32 independent loads in flight ----
        const int oc = bid - DD;             // 0..31
        const int obeg = oc * 16;
        const int k0 = tid;
        const int k1 = tid + 256;
        float acc0 = 0.f, acc1 = 0.f;
        #pragma unroll
        for (int i = 0; i < 16; ++i) {
            const int o = obeg + i;
            const int oc_ = o < DD ? o : DD - 1;      // clamp (last chunk)
            const float ww = o < DD ? W3[oc_] : 0.f;
            acc0 += ww * Wi[(size_t)oc_ * DD + k0];
            if (k1 < DD) acc1 += ww * Wi[(size_t)oc_ * DD + k1];
        }
        vpart[oc * VPSTRIDE + k0] = acc0;
        if (k1 < DD) vpart[oc * VPSTRIDE + k1] = acc1;
        return;
    }

    __shared__ float partial[4][BB];
    const int b = tid & 63;
    const int w = tid >> 6;
    const float* __restrict__ wrow = W + bid * DD;
    const int kbeg = w * 125;

    float a0 = 0.f, a1 = 0.f, a2 = 0.f, a3 = 0.f;
    float a4 = 0.f, a5 = 0.f, a6 = 0.f, a7 = 0.f;
    #pragma unroll 3
    for (int k = kbeg; k < kbeg + 120; k += 8) {   // 15 iters
        a0 += Ain[(k + 0) * BB + b] * wrow[k + 0];
        a1 += Ain[(k + 1) * BB + b] * wrow[k + 1];
        a2 += Ain[(k + 2) * BB + b] * wrow[k + 2];
        a3 += Ain[(k + 3) * BB + b] * wrow[k + 3];
        a4 += Ain[(k + 4) * BB + b] * wrow[k + 4];
        a5 += Ain[(k + 5) * BB + b] * wrow[k + 5];
        a6 += Ain[(k + 6) * BB + b] * wrow[k + 6];
        a7 += Ain[(k + 7) * BB + b] * wrow[k + 7];
    }
    {
        const int k = kbeg + 120;                  // 5-element tail
        a0 += Ain[(k + 0) * BB + b] * wrow[k + 0];
        a1 += Ain[(k + 1) * BB + b] * wrow[k + 1];
        a2 += Ain[(k + 2) * BB + b] * wrow[k + 2];
        a3 += Ain[(k + 3) * BB + b] * wrow[k + 3];
        a4 += Ain[(k + 4) * BB + b] * wrow[k + 4];
    }
    partial[w][b] = ((a0 + a1) + (a2 + a3)) + ((a4 + a5) + (a6 + a7));
    __syncthreads();
    if (w == 0) {
        float acc = bias[bid] + (partial[0][b] + partial[1][b])
                              + (partial[2][b] + partial[3][b]);
        acc = acc > 0.f ? acc : 0.01f * acc;
        Aout[bid * BB + b] = acc;
    }
}

// ---------------------------------------------------------------------------
// K2: blocks 0..499 compute h2T row (leaky dense, W2). Then each block fences
// its row and does ONE device-scope atomicAdd on counter (no spinning). The
// block that draws old==499 finalizes:
//   vv[k] = sum_oc vpart[oc][k];  out[b] = sigmoid(sum_k h2T[k][b]*vv[k]
//                                                  + sum_k W3[k]*bi[k] + b3)
// ---------------------------------------------------------------------------
__global__ __launch_bounds__(256) void k_dense2_out(
    const float* __restrict__ Ain, const float* __restrict__ W,
    const float* __restrict__ bias, float* __restrict__ h2T,
    const float* __restrict__ vpart, const float* __restrict__ W3,
    const float* __restrict__ bi, const float* __restrict__ b3,
    float* __restrict__ out, int* __restrict__ counter)
{
    __shared__ float partial[4][BB];
    __shared__ float vv[DD];
    __shared__ int isLast;
    const int tid = threadIdx.x;
    const int bid = blockIdx.x;
    const int b = tid & 63;
    const int w = tid >> 6;
    const float* __restrict__ wrow = W + bid * DD;
    const int kbeg = w * 125;

    float a0 = 0.f, a1 = 0.f, a2 = 0.f, a3 = 0.f;
    float a4 = 0.f, a5 = 0.f, a6 = 0.f, a7 = 0.f;
    #pragma unroll 3
    for (int k = kbeg; k < kbeg + 120; k += 8) {   // 15 iters
        a0 += Ain[(k + 0) * BB + b] * wrow[k + 0];
        a1 += Ain[(k + 1) * BB + b] * wrow[k + 1];
        a2 += Ain[(k + 2) * BB + b] * wrow[k + 2];
        a3 += Ain[(k + 3) * BB + b] * wrow[k + 3];
        a4 += Ain[(k + 4) * BB + b] * wrow[k + 4];
        a5 += Ain[(k + 5) * BB + b] * wrow[k + 5];
        a6 += Ain[(k + 6) * BB + b] * wrow[k + 6];
        a7 += Ain[(k + 7) * BB + b] * wrow[k + 7];
    }
    {
        const int k = kbeg + 120;                  // 5-element tail
        a0 += Ain[(k + 0) * BB + b] * wrow[k + 0];
        a1 += Ain[(k + 1) * BB + b] * wrow[k + 1];
        a2 += Ain[(k + 2) * BB + b] * wrow[k + 2];
        a3 += Ain[(k + 3) * BB + b] * wrow[k + 3];
        a4 += Ain[(k + 4) * BB + b] * wrow[k + 4];
    }
    partial[w][b] = ((a0 + a1) + (a2 + a3)) + ((a4 + a5) + (a6 + a7));
    __syncthreads();
    if (w == 0) {
        float acc = bias[bid] + (partial[0][b] + partial[1][b])
                              + (partial[2][b] + partial[3][b]);
        acc = acc > 0.f ? acc : 0.01f * acc;
        h2T[bid * BB + b] = acc;
        __threadfence();                 // make this block's row device-visible
    }
    __syncthreads();
    if (tid == 0) {
        int old = atomicAdd(counter, 1); // device-scope, one per block, no spin
        isLast = (old == DD - 1);
    }
    __syncthreads();
    if (!isLast) return;
    __threadfence();                     // acquire: all 500 rows now visible

    // ---- finalize (sole surviving block, ~1-2 us) ----
    // phase 1: vv[k] = sum_oc vpart[oc][k]
    for (int k = tid; k < DD; k += 256) {
        float s0 = 0.f, s1 = 0.f, s2 = 0.f, s3 = 0.f;
        float s4 = 0.f, s5 = 0.f, s6 = 0.f, s7 = 0.f;
        #pragma unroll
        for (int oc = 0; oc < VCHUNKS; oc += 8) {
            s0 += vpart[(oc + 0) * VPSTRIDE + k];
            s1 += vpart[(oc + 1) * VPSTRIDE + k];
            s2 += vpart[(oc + 2) * VPSTRIDE + k];
            s3 += vpart[(oc + 3) * VPSTRIDE + k];
            s4 += vpart[(oc + 4) * VPSTRIDE + k];
            s5 += vpart[(oc + 5) * VPSTRIDE + k];
            s6 += vpart[(oc + 6) * VPSTRIDE + k];
            s7 += vpart[(oc + 7) * VPSTRIDE + k];
        }
        vv[k] = ((s0 + s1) + (s2 + s3)) + ((s4 + s5) + (s6 + s7));
    }
    __syncthreads();

    // phase 2: out[b] = sigmoid( sum_k h2T[k][b]*vv[k] + W3.bi + b3 )
    {
        float p0 = 0.f, p1 = 0.f, p2 = 0.f, p3 = 0.f;
        for (int k = kbeg; k < kbeg + 124; k += 4) {
            p0 += h2T[(k + 0) * BB + b] * vv[k + 0] + W3[k + 0] * bi[k + 0];
            p1 += h2T[(k + 1) * BB + b] * vv[k + 1] + W3[k + 1] * bi[k + 1];
            p2 += h2T[(k + 2) * BB + b] * vv[k + 2] + W3[k + 2] * bi[k + 2];
            p3 += h2T[(k + 3) * BB + b] * vv[k + 3] + W3[k + 3] * bi[k + 3];
        }
        {
            const int k = kbeg + 124;
            p0 += h2T[k * BB + b] * vv[k] + W3[k] * bi[k];
        }
        partial[w][b] = (p0 + p1) + (p2 + p3);
    }
    __syncthreads();
    if (w == 0) {
        float s = b3[0] + (partial[0][b] + partial[1][b])
                        + (partial[2][b] + partial[3][b]);
        out[b] = 1.f / (1.f + __expf(-s));
    }
}

// ---------------------------------------------------------------------------
extern "C" void kernel_launch(void* const* d_in, const int* in_sizes, int n_in,
                              void* d_out, int out_size, void* d_ws, size_t ws_size,
                              hipStream_t stream)
{
    const float* pitches    = (const float*)d_in[0];
    const float* velocities = (const float*)d_in[1];
    const float* durations  = (const float*)d_in[2];
    const float* steps      = (const float*)d_in[3];
    const float* Wp  = (const float*)d_in[4];
    const float* bp  = (const float*)d_in[5];
    const float* Wv  = (const float*)d_in[6];
    const float* bv  = (const float*)d_in[7];
    const float* Wd  = (const float*)d_in[8];
    const float* bd  = (const float*)d_in[9];
    const float* Wst = (const float*)d_in[10];
    const float* bs  = (const float*)d_in[11];
    const float* W1  = (const float*)d_in[12];
    const float* b1  = (const float*)d_in[13];
    const float* W2  = (const float*)d_in[14];
    const float* b2  = (const float*)d_in[15];
    const float* Wi  = (const float*)d_in[16];
    const float* bi  = (const float*)d_in[17];
    const float* W3  = (const float*)d_in[18];
    const float* b3  = (const float*)d_in[19];

    float* ws    = (float*)d_ws;
    float* addT  = ws;                                    // 500*64
    float* h1T   = ws + 32000;                            // 500*64
    float* h2T   = ws + 64000;                            // 500*64
    float* vpart = ws + 96000;                            // 32*512
    int*   counter = (int*)(ws + 96000 + VCHUNKS * VPSTRIDE);

    float* out = (float*)d_out;   // [64,1] fp32

    k_embed<<<125, 256, 0, stream>>>(pitches, velocities, durations, steps,
                                     Wp, bp, Wv, bv, Wd, bd, Wst, bs, addT);
    k_dense1<<<DD + VCHUNKS, 256, 0, stream>>>(addT, W1, b1, h1T,
                                               Wi, W3, vpart, counter);
    k_dense2_out<<<DD, 256, 0, stream>>>(h1T, W2, b2, h2T,
                                         vpart, W3, bi, b3, out, counter);
}

// Round 8
// 188.961 us; speedup vs baseline: 1.0703x; 1.0703x over previous
//
#include <hip/hip_runtime.h>

#define DD 500   // hidden width
#define BB 64    // batch
#define TT 2048  // timesteps (only last matters)
#define KP 128   // pitch/velocity feature width
#define VCHUNKS 32
#define VPSTRIDE 512

// ---------------------------------------------------------------------------
// K0: embed (last timestep only) -> addT[500][64]
// 125 blocks: 4 o-rows x 64 b each, via swizzled-LDS transpose of P/V slices
// ---------------------------------------------------------------------------
__global__ __launch_bounds__(256) void k_embed(
    const float* __restrict__ pitches, const float* __restrict__ velocities,
    const float* __restrict__ durations, const float* __restrict__ steps,
    const float* __restrict__ Wp, const float* __restrict__ bp,
    const float* __restrict__ Wv, const float* __restrict__ bv,
    const float* __restrict__ Wd, const float* __restrict__ bd,
    const float* __restrict__ Wst, const float* __restrict__ bs,
    float* __restrict__ addT)
{
    const int tid = threadIdx.x;
    const int bid = blockIdx.x;

    __shared__ float lds[KP * BB];  // 32 KB; [k][b] at lds[k*64 + ((b+k)&63)]
    const int b = tid & 63;
    const int o = __builtin_amdgcn_readfirstlane(bid * 4 + (tid >> 6));
    const float* __restrict__ wp = Wp + o * KP;
    const float* __restrict__ wv = Wv + o * KP;

    float a0 = 0.f, a1 = 0.f, a2 = 0.f, a3 = 0.f;

    const float4* Psrc = (const float4*)(pitches + (size_t)(TT - 1) * BB * KP);
    const float4* Vsrc = (const float4*)(velocities + (size_t)(TT - 1) * BB * KP);

    // pass 1: pitches
    for (int j = tid; j < BB * KP / 4; j += 256) {
        float4 p = Psrc[j];
        int pb = j >> 5;          // batch row (32 float4 per 128-wide row)
        int k0 = (j & 31) * 4;
        lds[(k0 + 0) * BB + ((pb + k0 + 0) & 63)] = p.x;
        lds[(k0 + 1) * BB + ((pb + k0 + 1) & 63)] = p.y;
        lds[(k0 + 2) * BB + ((pb + k0 + 2) & 63)] = p.z;
        lds[(k0 + 3) * BB + ((pb + k0 + 3) & 63)] = p.w;
    }
    __syncthreads();
    for (int k = 0; k < KP; k += 4) {
        a0 += lds[(k + 0) * BB + ((b + k + 0) & 63)] * wp[k + 0];
        a1 += lds[(k + 1) * BB + ((b + k + 1) & 63)] * wp[k + 1];
        a2 += lds[(k + 2) * BB + ((b + k + 2) & 63)] * wp[k + 2];
        a3 += lds[(k + 3) * BB + ((b + k + 3) & 63)] * wp[k + 3];
    }
    __syncthreads();

    // pass 2: velocities
    for (int j = tid; j < BB * KP / 4; j += 256) {
        float4 p = Vsrc[j];
        int pb = j >> 5;
        int k0 = (j & 31) * 4;
        lds[(k0 + 0) * BB + ((pb + k0 + 0) & 63)] = p.x;
        lds[(k0 + 1) * BB + ((pb + k0 + 1) & 63)] = p.y;
        lds[(k0 + 2) * BB + ((pb + k0 + 2) & 63)] = p.z;
        lds[(k0 + 3) * BB + ((pb + k0 + 3) & 63)] = p.w;
    }
    __syncthreads();
    for (int k = 0; k < KP; k += 4) {
        a0 += lds[(k + 0) * BB + ((b + k + 0) & 63)] * wv[k + 0];
        a1 += lds[(k + 1) * BB + ((b + k + 1) & 63)] * wv[k + 1];
        a2 += lds[(k + 2) * BB + ((b + k + 2) & 63)] * wv[k + 2];
        a3 += lds[(k + 3) * BB + ((b + k + 3) & 63)] * wv[k + 3];
    }

    const float dur = durations[(size_t)(TT - 1) * BB + b];
    const float st  = steps[(size_t)(TT - 1) * BB + b];
    addT[o * BB + b] = bp[o] + bv[o] + bd[o] + bs[o]
                     + dur * Wd[o] + st * Wst[o]
                     + (a0 + a1) + (a2 + a3);
}

// ---------------------------------------------------------------------------
// K1/K2: one o-row per block; 4 waves k-split (125 k's each) + LDS reduce.
// lanes = b (coalesced 256B activation reads), weights wave-uniform s_loads.
// Dense-1 additionally carries 32 v-chunk blocks (bid 500..531):
//   vpart[oc][k] = sum_{o in chunk oc} W3[o] * Wi[o*500+k]  (k_out-only input,
//   independent of dense-1's output -> legal to overlap here)
// ---------------------------------------------------------------------------
__global__ __launch_bounds__(256) void k_dense(
    const float* __restrict__ Ain, const float* __restrict__ W,
    const float* __restrict__ bias, float* __restrict__ Aout, int leaky,
    const float* __restrict__ Wi, const float* __restrict__ W3,
    float* __restrict__ vpart)
{
    const int tid = threadIdx.x;
    const int bid = blockIdx.x;

    if (bid >= DD) {
        // ---- v-chunk: 16 o-rows, 32 independent loads in flight ----
        const int oc = bid - DD;             // 0..31
        const int obeg = oc * 16;
        const int k0 = tid;
        const int k1 = tid + 256;
        float acc0 = 0.f, acc1 = 0.f;
        #pragma unroll
        for (int i = 0; i < 16; ++i) {
            const int o = obeg + i;
            const int oc_ = o < DD ? o : DD - 1;      // clamp (last chunk)
            const float ww = o < DD ? W3[oc_] : 0.f;
            acc0 += ww * Wi[(size_t)oc_ * DD + k0];
            if (k1 < DD) acc1 += ww * Wi[(size_t)oc_ * DD + k1];
        }
        vpart[oc * VPSTRIDE + k0] = acc0;
        if (k1 < DD) vpart[oc * VPSTRIDE + k1] = acc1;
        return;
    }

    __shared__ float partial[4][BB];
    const int b = tid & 63;
    const int w = tid >> 6;
    const int o = bid;                        // 0..499
    const float* __restrict__ wrow = W + o * DD;
    const int kbeg = w * 125;

    float a0 = 0.f, a1 = 0.f, a2 = 0.f, a3 = 0.f;
    float a4 = 0.f, a5 = 0.f, a6 = 0.f, a7 = 0.f;
    #pragma unroll 3
    for (int k = kbeg; k < kbeg + 120; k += 8) {   // 15 iters
        a0 += Ain[(k + 0) * BB + b] * wrow[k + 0];
        a1 += Ain[(k + 1) * BB + b] * wrow[k + 1];
        a2 += Ain[(k + 2) * BB + b] * wrow[k + 2];
        a3 += Ain[(k + 3) * BB + b] * wrow[k + 3];
        a4 += Ain[(k + 4) * BB + b] * wrow[k + 4];
        a5 += Ain[(k + 5) * BB + b] * wrow[k + 5];
        a6 += Ain[(k + 6) * BB + b] * wrow[k + 6];
        a7 += Ain[(k + 7) * BB + b] * wrow[k + 7];
    }
    {
        const int k = kbeg + 120;                  // 5-element tail
        a0 += Ain[(k + 0) * BB + b] * wrow[k + 0];
        a1 += Ain[(k + 1) * BB + b] * wrow[k + 1];
        a2 += Ain[(k + 2) * BB + b] * wrow[k + 2];
        a3 += Ain[(k + 3) * BB + b] * wrow[k + 3];
        a4 += Ain[(k + 4) * BB + b] * wrow[k + 4];
    }
    partial[w][b] = ((a0 + a1) + (a2 + a3)) + ((a4 + a5) + (a6 + a7));
    __syncthreads();
    if (w == 0) {
        float acc = bias[o] + (partial[0][b] + partial[1][b])
                            + (partial[2][b] + partial[3][b]);
        if (leaky) acc = acc > 0.f ? acc : 0.01f * acc;
        Aout[o * BB + b] = acc;
    }
}

// ---------------------------------------------------------------------------
// K3 (one 1024-thread block, 16 waves):
//  phase 1: vv[k] = sum_oc vpart[oc][k]  (one pass, 500 threads, 8 in flight)
//  phase 2: wave w covers k in [w*32, min(w*32+32,500));
//           out[b] = sigmoid( sum_k h2T[k][b]*vv[k] + W3.bi + b3 )
// ---------------------------------------------------------------------------
__global__ __launch_bounds__(1024) void k_out(
    const float* __restrict__ h2T, const float* __restrict__ vpart,
    const float* __restrict__ W3, const float* __restrict__ bi,
    const float* __restrict__ b3, float* __restrict__ out)
{
    __shared__ float vv[DD];
    __shared__ float partial[16][BB];
    const int tid = threadIdx.x;

    // phase 1: reduce 32 partials for this thread's k (8 loads in flight)
    if (tid < DD) {
        const int k = tid;
        float s0 = 0.f, s1 = 0.f, s2 = 0.f, s3 = 0.f;
        float s4 = 0.f, s5 = 0.f, s6 = 0.f, s7 = 0.f;
        #pragma unroll
        for (int oc = 0; oc < VCHUNKS; oc += 8) {
            s0 += vpart[(oc + 0) * VPSTRIDE + k];
            s1 += vpart[(oc + 1) * VPSTRIDE + k];
            s2 += vpart[(oc + 2) * VPSTRIDE + k];
            s3 += vpart[(oc + 3) * VPSTRIDE + k];
            s4 += vpart[(oc + 4) * VPSTRIDE + k];
            s5 += vpart[(oc + 5) * VPSTRIDE + k];
            s6 += vpart[(oc + 6) * VPSTRIDE + k];
            s7 += vpart[(oc + 7) * VPSTRIDE + k];
        }
        vv[k] = ((s0 + s1) + (s2 + s3)) + ((s4 + s5) + (s6 + s7));
    }
    __syncthreads();

    const int b = tid & 63;
    const int w = tid >> 6;                // 0..15
    const int kbeg = w * 32;
    const int kend = kbeg + 32 < DD ? kbeg + 32 : DD;

    float accA = 0.f, accB = 0.f, accC = 0.f, accD = 0.f;
    for (int k = kbeg; k < kend; k += 4) {
        accA += h2T[(k + 0) * BB + b] * vv[k + 0];
        accB += h2T[(k + 1) * BB + b] * vv[k + 1];
        accC += h2T[(k + 2) * BB + b] * vv[k + 2];
        accD += h2T[(k + 3) * BB + b] * vv[k + 3];
        accA += W3[k + 0] * bi[k + 0];
        accB += W3[k + 1] * bi[k + 1];
        accC += W3[k + 2] * bi[k + 2];
        accD += W3[k + 3] * bi[k + 3];
    }
    partial[w][b] = (accA + accB) + (accC + accD);
    __syncthreads();
    if (w == 0) {
        float s = b3[0];
        #pragma unroll
        for (int i = 0; i < 16; ++i) s += partial[i][b];
        out[b] = 1.f / (1.f + __expf(-s));
    }
}

// ---------------------------------------------------------------------------
extern "C" void kernel_launch(void* const* d_in, const int* in_sizes, int n_in,
                              void* d_out, int out_size, void* d_ws, size_t ws_size,
                              hipStream_t stream)
{
    const float* pitches    = (const float*)d_in[0];
    const float* velocities = (const float*)d_in[1];
    const float* durations  = (const float*)d_in[2];
    const float* steps      = (const float*)d_in[3];
    const float* Wp  = (const float*)d_in[4];
    const float* bp  = (const float*)d_in[5];
    const float* Wv  = (const float*)d_in[6];
    const float* bv  = (const float*)d_in[7];
    const float* Wd  = (const float*)d_in[8];
    const float* bd  = (const float*)d_in[9];
    const float* Wst = (const float*)d_in[10];
    const float* bs  = (const float*)d_in[11];
    const float* W1  = (const float*)d_in[12];
    const float* b1  = (const float*)d_in[13];
    const float* W2  = (const float*)d_in[14];
    const float* b2  = (const float*)d_in[15];
    const float* Wi  = (const float*)d_in[16];
    const float* bi  = (const float*)d_in[17];
    const float* W3  = (const float*)d_in[18];
    const float* b3  = (const float*)d_in[19];

    float* ws    = (float*)d_ws;
    float* addT  = ws;            // 500*64
    float* h1T   = ws + 32000;    // 500*64
    float* h2T   = ws + 64000;    // 500*64
    float* vpart = ws + 96000;    // 32*512

    float* out = (float*)d_out;   // [64,1] fp32

    k_embed<<<125, 256, 0, stream>>>(pitches, velocities, durations, steps,
                                     Wp, bp, Wv, bv, Wd, bd, Wst, bs, addT);
    // dense-1 carries the 32 vpart blocks (overlapped; vpart only feeds k_out)
    k_dense<<<DD + VCHUNKS, 256, 0, stream>>>(addT, W1, b1, h1T, 1,
                                              Wi, W3, vpart);
    k_dense<<<DD, 256, 0, stream>>>(h1T, W2, b2, h2T, 1, Wi, W3, vpart);
    k_out<<<1, 1024, 0, stream>>>(h2T, vpart, W3, bi, b3, out);
}